// Round 3
// baseline (16071.983 us; speedup 1.0000x reference)
//
#include <hip/hip_runtime.h>
#include <hip/hip_bf16.h>
#include <cstddef>

#define BN_EPS 1e-5f

__device__ __forceinline__ float sigmoidf_(float x) {
    return 1.f / (1.f + __expf(-x));
}
__device__ __forceinline__ float tanhf_(float x) {
    float e = __expf(2.f * x);
    return 1.f - 2.f / (e + 1.f);
}

// ---------------------------------------------------------------------------
// Fused conv3x3(SAME) + bias + BN + ReLU + maxpool2x2 block.
// One thread per pooled output pixel; computes the 2x2 pre-pool conv window.
// Block handles one (img, oc, quad-of-256-pooled-pixels); weights in LDS.
// Launched per image-group: `in`/`out` are group-base pointers, img is local.
// ---------------------------------------------------------------------------
template <int CI, int OC, int S>
__global__ __launch_bounds__(256) void cnn_block_kernel(
    const float* __restrict__ in, const float* __restrict__ w,
    const float* __restrict__ bias, const float* __restrict__ g,
    const float* __restrict__ be, const float* __restrict__ m,
    const float* __restrict__ v, float* __restrict__ out)
{
    constexpr int PS = S / 2;             // pooled spatial
    constexpr int NQ = (PS * PS) / 256;   // 256-thread quads per (img, oc)
    __shared__ float wl[CI * 9];

    int bid  = blockIdx.x;
    int quad = bid % NQ;
    int t2   = bid / NQ;
    int oc   = t2 % OC;
    int img  = t2 / OC;                   // local within group
    int tid  = threadIdx.x;

    const float* wsrc = w + (size_t)oc * CI * 9;
    for (int i = tid; i < CI * 9; i += 256) wl[i] = wsrc[i];
    __syncthreads();

    int pp = quad * 256 + tid;
    int pr = pp / PS, pc = pp % PS;
    int r0 = 2 * pr - 1, c0 = 2 * pc - 1;

    int  roff[4], coff[4];
    bool rok[4], cok[4];
#pragma unroll
    for (int i = 0; i < 4; i++) {
        int rr = r0 + i; rok[i] = (rr >= 0 && rr < S); roff[i] = min(max(rr, 0), S - 1) * S;
        int cc = c0 + i; cok[i] = (cc >= 0 && cc < S); coff[i] = min(max(cc, 0), S - 1);
    }

    float acc00 = 0.f, acc01 = 0.f, acc10 = 0.f, acc11 = 0.f;
    const float* ip = in + (size_t)img * CI * S * S;
    for (int ci = 0; ci < CI; ++ci) {
        float patch[4][4];
#pragma unroll
        for (int iy = 0; iy < 4; iy++)
#pragma unroll
            for (int ix = 0; ix < 4; ix++) {
                float val = ip[roff[iy] + coff[ix]];
                patch[iy][ix] = (rok[iy] && cok[ix]) ? val : 0.f;
            }
        const float* wp = wl + ci * 9;
#pragma unroll
        for (int ky = 0; ky < 3; ky++)
#pragma unroll
            for (int kx = 0; kx < 3; kx++) {
                float ww = wp[ky * 3 + kx];
                acc00 += ww * patch[ky][kx];
                acc01 += ww * patch[ky][kx + 1];
                acc10 += ww * patch[ky + 1][kx];
                acc11 += ww * patch[ky + 1][kx + 1];
            }
        ip += S * S;
    }

    float scale = g[oc] * rsqrtf(v[oc] + BN_EPS);
    float shift = be[oc] - m[oc] * scale + bias[oc] * scale;
    float r00 = fmaxf(acc00 * scale + shift, 0.f);
    float r01 = fmaxf(acc01 * scale + shift, 0.f);
    float r10 = fmaxf(acc10 * scale + shift, 0.f);
    float r11 = fmaxf(acc11 * scale + shift, 0.f);
    float mx = fmaxf(fmaxf(r00, r01), fmaxf(r10, r11));

    out[((size_t)(img * OC + oc) * PS + pr) * PS + pc] = mx;
}

// ---------------------------------------------------------------------------
// ConvLSTM gate pre-activation conv: z = conv3x3(concat[x, h]) + bias.
// One block per (batch b, z-channel zc); 256 threads = 16x16 pixels.
// Weight row (512*9 floats = 18KB) staged in LDS.
// ---------------------------------------------------------------------------
__global__ __launch_bounds__(256) void lstm_conv_kernel(
    const float* __restrict__ x, int xstrideB,
    const float* __restrict__ h, int hstrideB,
    const float* __restrict__ w,     // (1024, 512, 3, 3)
    const float* __restrict__ bias,  // (1024)
    float* __restrict__ z)           // (2, 1024, 256)
{
    __shared__ float wl[4608];
    int bid = blockIdx.x;
    int b   = bid & 1;
    int zc  = bid >> 1;
    int tid = threadIdx.x;

    const float* wsrc = w + (size_t)zc * 4608;
    for (int i = tid; i < 4608; i += 256) wl[i] = wsrc[i];
    __syncthreads();

    int py = tid >> 4, px = tid & 15;
    int  off[9];
    bool ok[9];
#pragma unroll
    for (int ky = 0; ky < 3; ky++)
#pragma unroll
        for (int kx = 0; kx < 3; kx++) {
            int yy = py + ky - 1, xx = px + kx - 1;
            ok[ky * 3 + kx]  = (yy >= 0 && yy < 16 && xx >= 0 && xx < 16);
            off[ky * 3 + kx] = min(max(yy, 0), 15) * 16 + min(max(xx, 0), 15);
        }

    float acc = bias[zc];
    const float* wp = wl;

    const float* xp = x + (size_t)b * xstrideB;
    for (int ci = 0; ci < 256; ++ci) {
#pragma unroll
        for (int k = 0; k < 9; k++) {
            float val = xp[off[k]];
            acc += wp[k] * (ok[k] ? val : 0.f);
        }
        xp += 256; wp += 9;
    }
    const float* hp = h + (size_t)b * hstrideB;
    for (int ci = 0; ci < 256; ++ci) {
#pragma unroll
        for (int k = 0; k < 9; k++) {
            float val = hp[off[k]];
            acc += wp[k] * (ok[k] ? val : 0.f);
        }
        hp += 256; wp += 9;
    }

    z[((size_t)b * 1024 + zc) * 256 + tid] = acc;
}

// ---------------------------------------------------------------------------
// Gate combine: c = sig(f)*c + sig(i)*tanh(g); h = sig(o)*tanh(c).
// 131072 threads (b=2, ch=256, px=256). Outputs are FLOAT32 (reference dtype).
// ---------------------------------------------------------------------------
__global__ __launch_bounds__(256) void lstm_gates_kernel(
    const float* __restrict__ z, float* __restrict__ c,
    float* __restrict__ hnew, int hstrideB,
    float* __restrict__ outseq,   // base for t-slot (stride b: 16*65536); may be null
    float* __restrict__ outlast)  // may be null
{
    int idx = blockIdx.x * 256 + threadIdx.x;  // 0..131071
    int b = idx >> 16;
    int r = idx & 65535;  // ch*256 + px

    const float* zb = z + (size_t)b * 262144;
    float zi = zb[r];
    float zf = zb[65536 + r];
    float zo = zb[131072 + r];
    float zg = zb[196608 + r];

    float* cp   = c + (size_t)b * 65536 + r;
    float  cold = *cp;
    float  cn   = sigmoidf_(zf) * cold + sigmoidf_(zi) * tanhf_(zg);
    float  hn   = sigmoidf_(zo) * tanhf_(cn);
    *cp = cn;

    hnew[(size_t)b * hstrideB + r] = hn;
    if (outseq)  outseq[(size_t)b * 1048576 + r] = hn;
    if (outlast) outlast[(size_t)b * 65536 + r]  = hn;
}

// ---------------------------------------------------------------------------
extern "C" void kernel_launch(void* const* d_in, const int* in_sizes, int n_in,
                              void* d_out, int out_size, void* d_ws, size_t ws_size,
                              hipStream_t stream)
{
    const float* x   = (const float*)d_in[0];
    const float* w0  = (const float*)d_in[1];
    const float* b0  = (const float*)d_in[2];
    const float* g0  = (const float*)d_in[3];
    const float* be0 = (const float*)d_in[4];
    const float* m0  = (const float*)d_in[5];
    const float* v0  = (const float*)d_in[6];
    const float* w1  = (const float*)d_in[7];
    const float* b1  = (const float*)d_in[8];
    const float* g1  = (const float*)d_in[9];
    const float* be1 = (const float*)d_in[10];
    const float* m1  = (const float*)d_in[11];
    const float* v1  = (const float*)d_in[12];
    const float* w2  = (const float*)d_in[13];
    const float* b2  = (const float*)d_in[14];
    const float* g2  = (const float*)d_in[15];
    const float* be2 = (const float*)d_in[16];
    const float* m2  = (const float*)d_in[17];
    const float* v2  = (const float*)d_in[18];
    const float* lw0 = (const float*)d_in[19];
    const float* lb0 = (const float*)d_in[20];
    const float* lw1 = (const float*)d_in[21];
    const float* lb1 = (const float*)d_in[22];

    float* out = (float*)d_out;   // reference output dtype is float32

    // ---- compact workspace plan: 5,242,880 floats = 20 MiB peak ----
    float* ws  = (float*)d_ws;
    float* y2  = ws;                 // [0, 2097152)  persists through LSTM layer 0
    // CNN per-group scratch (8 images per group, 4 groups):
    float* y0g = ws + 2097152;       // [2097152, 4194304)   8 img * 64ch * 64*64
    float* y1g = ws + 4194304;       // [4194304, 5242880)   8 img * 128ch * 32*32
    // LSTM region overlays y0g/y1g after the CNN is done:
    float* h0s   = ws + 2097152;     // 2,097,152 floats (layer-0 h sequence, (b,t,c,px))
    float* ztmp  = ws + 4194304;     // 524,288
    float* hzero = ws + 4718592;     // 131,072
    float* cbuf0 = ws + 4849664;     // 131,072
    float* cbuf1 = ws + 4980736;     // 131,072
    float* hbuf1 = ws + 5111808;     // 131,072

    // ---- CNN encoder, tiled over 4 groups of 8 images ----
    for (int g = 0; g < 4; ++g) {
        const float* xg = x + (size_t)g * 8 * 16384;          // 8 img * 1ch * 128*128
        cnn_block_kernel<1, 64, 128><<<8 * 64 * 16, 256, 0, stream>>>(
            xg, w0, b0, g0, be0, m0, v0, y0g);
        cnn_block_kernel<64, 128, 64><<<8 * 128 * 4, 256, 0, stream>>>(
            y0g, w1, b1, g1, be1, m1, v1, y1g);
        cnn_block_kernel<128, 256, 32><<<8 * 256 * 1, 256, 0, stream>>>(
            y1g, w2, b2, g2, be2, m2, v2, y2 + (size_t)g * 8 * 65536);
    }

    // zero hzero + cbuf0 + cbuf1 + hbuf1 (contiguous)
    hipMemsetAsync(hzero, 0, (size_t)4 * 131072 * sizeof(float), stream);

    // ---- ConvLSTM layer 0 ----
    // y2 layout: ((b*16 + t)*256 + c)*256 + px  -> batch stride 16*65536, t stride 65536
    for (int t = 0; t < 16; ++t) {
        const float* hprev = (t == 0) ? hzero : (h0s + (size_t)(t - 1) * 65536);
        int hstride = (t == 0) ? 0 : 16 * 65536;
        lstm_conv_kernel<<<2048, 256, 0, stream>>>(
            y2 + (size_t)t * 65536, 16 * 65536, hprev, hstride, lw0, lb0, ztmp);
        lstm_gates_kernel<<<512, 256, 0, stream>>>(
            ztmp, cbuf0, h0s + (size_t)t * 65536, 16 * 65536, nullptr, nullptr);
    }

    // ---- ConvLSTM layer 1 ----
    for (int t = 0; t < 16; ++t) {
        const float* hprev = (t == 0) ? hzero : hbuf1;
        int hstride = (t == 0) ? 0 : 65536;
        lstm_conv_kernel<<<2048, 256, 0, stream>>>(
            h0s + (size_t)t * 65536, 16 * 65536, hprev, hstride, lw1, lb1, ztmp);
        lstm_gates_kernel<<<512, 256, 0, stream>>>(
            ztmp, cbuf1, hbuf1, 65536,
            out + (size_t)t * 65536,
            (t == 15) ? (out + 2097152) : nullptr);
    }
}

// Round 5
// 3770.299 us; speedup vs baseline: 4.2628x; 4.2628x over previous
//
#include <hip/hip_runtime.h>
#include <hip/hip_bf16.h>
#include <cstddef>

#define BN_EPS 1e-5f

typedef __attribute__((ext_vector_type(8))) _Float16 half8;
typedef __attribute__((ext_vector_type(4))) float f32x4;

__device__ __forceinline__ float sigmoidf_(float x) {
    return 1.f / (1.f + __expf(-x));
}
__device__ __forceinline__ float tanhf_(float x) {
    float e = __expf(2.f * x);
    return 1.f - 2.f / (e + 1.f);
}

// ---------------------------------------------------------------------------
// Fused conv3x3(SAME) + bias + BN + ReLU + maxpool2x2 block (scalar, fp32).
// One thread per pooled output pixel; each block computes OCB output channels
// from a single patch load (amortizes the 16 loads across OCB*36 FMAs).
// ---------------------------------------------------------------------------
template <int CI, int OC, int S, int OCB, typename OT>
__global__ __launch_bounds__(256) void cnn_block_kernel(
    const float* __restrict__ in, const float* __restrict__ w,
    const float* __restrict__ bias, const float* __restrict__ g,
    const float* __restrict__ be, const float* __restrict__ m,
    const float* __restrict__ v, OT* __restrict__ out)
{
    constexpr int PS  = S / 2;
    constexpr int NQ  = (PS * PS) / 256;
    constexpr int NOG = OC / OCB;
    __shared__ float wl[OCB * CI * 9];

    int bid  = blockIdx.x;
    int quad = bid % NQ;
    int t2   = bid / NQ;
    int ocg  = t2 % NOG;
    int img  = t2 / NOG;
    int tid  = threadIdx.x;
    int oc0  = ocg * OCB;

    const float* wsrc = w + (size_t)oc0 * CI * 9;
    for (int i = tid; i < OCB * CI * 9; i += 256) wl[i] = wsrc[i];
    __syncthreads();

    int pp = quad * 256 + tid;
    int pr = pp / PS, pc = pp % PS;
    int r0 = 2 * pr - 1, c0 = 2 * pc - 1;

    int  roff[4], coff[4];
    bool rok[4], cok[4];
#pragma unroll
    for (int i = 0; i < 4; i++) {
        int rr = r0 + i; rok[i] = (rr >= 0 && rr < S); roff[i] = min(max(rr, 0), S - 1) * S;
        int cc = c0 + i; cok[i] = (cc >= 0 && cc < S); coff[i] = min(max(cc, 0), S - 1);
    }

    float acc[OCB][4];
#pragma unroll
    for (int o = 0; o < OCB; o++)
#pragma unroll
        for (int j = 0; j < 4; j++) acc[o][j] = 0.f;

    const float* ip = in + (size_t)img * CI * S * S;
    for (int ci = 0; ci < CI; ++ci) {
        float patch[4][4];
#pragma unroll
        for (int iy = 0; iy < 4; iy++)
#pragma unroll
            for (int ix = 0; ix < 4; ix++) {
                float val = ip[roff[iy] + coff[ix]];
                patch[iy][ix] = (rok[iy] && cok[ix]) ? val : 0.f;
            }
#pragma unroll
        for (int o = 0; o < OCB; o++) {
            const float* wp = wl + ((size_t)o * CI + ci) * 9;
#pragma unroll
            for (int ky = 0; ky < 3; ky++)
#pragma unroll
                for (int kx = 0; kx < 3; kx++) {
                    float ww = wp[ky * 3 + kx];
                    acc[o][0] += ww * patch[ky][kx];
                    acc[o][1] += ww * patch[ky][kx + 1];
                    acc[o][2] += ww * patch[ky + 1][kx];
                    acc[o][3] += ww * patch[ky + 1][kx + 1];
                }
        }
        ip += S * S;
    }

#pragma unroll
    for (int o = 0; o < OCB; o++) {
        int oc = oc0 + o;
        float scale = g[oc] * rsqrtf(v[oc] + BN_EPS);
        float shift = be[oc] - m[oc] * scale + bias[oc] * scale;
        float r00 = fmaxf(acc[o][0] * scale + shift, 0.f);
        float r01 = fmaxf(acc[o][1] * scale + shift, 0.f);
        float r10 = fmaxf(acc[o][2] * scale + shift, 0.f);
        float r11 = fmaxf(acc[o][3] * scale + shift, 0.f);
        float mx = fmaxf(fmaxf(r00, r01), fmaxf(r10, r11));
        out[((size_t)(img * OC + oc) * PS + pr) * PS + pc] = (OT)mx;
    }
}

// ---------------------------------------------------------------------------
// Weight permute+convert: Wp[row'=c*4+gate][k'=part*2304+tap*256+ci] (fp16)
// from W[zc=gate*256+c][cin=part*256+ci][tap] (fp32).
// ---------------------------------------------------------------------------
__global__ __launch_bounds__(256) void wprep_kernel(
    const float* __restrict__ W, _Float16* __restrict__ Wp)
{
    int idx   = blockIdx.x * 256 + threadIdx.x;   // 0 .. 1024*576-1
    int row   = idx / 576;
    int chunk = idx % 576;
    int k0    = chunk * 8;
    int c = row >> 2, ggate = row & 3;
    int zc = ggate * 256 + c;
    int p   = (k0 >= 2304) ? 1 : 0;
    int rem = k0 - p * 2304;
    int tap = rem >> 8;
    int ci  = rem & 255;
    const float* src = W + (size_t)zc * 4608 + (size_t)(p * 256 + ci) * 9 + tap;
    _Float16* dst = Wp + (size_t)row * 4608 + k0;
#pragma unroll
    for (int j = 0; j < 8; ++j) dst[j] = (_Float16)src[(size_t)j * 9];
}

// ---------------------------------------------------------------------------
// Fused ConvLSTM step: implicit-GEMM conv3x3 (M=1024 gate-interleaved rows,
// N=512 = 2 img x 256 px, K=4608) + LSTM cell epilogue. fp16 MFMA 16x16x32.
// 128 threads = 2 waves. Grid: 512 blocks = 32 (M) x 16 (N).
// ---------------------------------------------------------------------------
template <bool WRITE_SEQ>
__global__ __launch_bounds__(128) void lstm_step_kernel(
    const _Float16* __restrict__ Wp, const float* __restrict__ lbias,
    const _Float16* __restrict__ xsrc, long xs,
    const _Float16* __restrict__ hsrc, long hs,
    float* __restrict__ cstate,
    _Float16* __restrict__ hdst, long hds,
    float* __restrict__ outseq, long osb,
    float* __restrict__ outlast)
{
    __shared__ _Float16 Al[2][2048];   // [32 rows][32 k] swizzled, x2 buffers
    __shared__ _Float16 Bl[2][2048];   // [32 n][32 k] swizzled

    const int tid = threadIdx.x;
    const int bm  = blockIdx.x & 31;
    const int bnb = blockIdx.x >> 5;        // 0..15
    const int img = bnb >> 3;               // 0..1
    const int px0 = (bnb & 7) * 32;

    const int srow = tid >> 2;
    const int kc   = tid & 3;
    const int lw_off = srow * 64 + ((kc ^ ((srow >> 1) & 3)) << 4);  // bytes

    const _Float16* gA = Wp + (size_t)(bm * 32 + srow) * 4608 + kc * 8;

    const int p_pix = px0 + srow;
    const int py = p_pix >> 4, px = p_pix & 15;

    const _Float16* srcX = xsrc + (size_t)img * xs;
    const _Float16* srcH = hsrc + (size_t)img * hs;

    const int lane = tid & 63;
    const int wm   = tid >> 6;
    const int kq   = lane >> 4;
    const int acol = lane & 15;
    const int arow = wm * 16 + acol;
    const int a_off  = arow * 64 + ((kq ^ ((arow >> 1) & 3)) << 4);
    const int b_off0 = acol * 64 + ((kq ^ ((acol >> 1) & 3)) << 4);
    const int brow1  = 16 + acol;
    const int b_off1 = brow1 * 64 + ((kq ^ ((brow1 >> 1) & 3)) << 4);

    f32x4 acc0 = {0.f, 0.f, 0.f, 0.f};
    f32x4 acc1 = {0.f, 0.f, 0.f, 0.f};

    const int KSTEPS = 144;   // 4608 / 32

    half8 av, bv;
    auto load_step = [&](int s) {
        int k0  = s * 32;
        int pth = (k0 >= 2304) ? 1 : 0;
        int rem = k0 - pth * 2304;
        int tap = rem >> 8;                 // uniform per step
        int ci  = (rem & 255) + kc * 8;
        int dy = tap / 3 - 1, dx = tap % 3 - 1;
        int yy = py + dy, xx = px + dx;
        bool ok = (yy >= 0) && (yy < 16) && (xx >= 0) && (xx < 16);
        int soff = ok ? (yy * 16 + xx) : 0;
        const _Float16* s_ = (pth ? srcH : srcX) + (size_t)ci * 256 + soff;
        av = *(const half8*)(gA + k0);
#pragma unroll
        for (int j = 0; j < 8; ++j) {
            _Float16 v_ = s_[(size_t)j * 256];
            bv[j] = ok ? v_ : (_Float16)0.f;
        }
    };
    auto store_lds = [&](int buf) {
        *(half8*)((char*)&Al[buf][0] + lw_off) = av;
        *(half8*)((char*)&Bl[buf][0] + lw_off) = bv;
    };

    load_step(0);
    store_lds(0);
    __syncthreads();

    for (int s = 0; s < KSTEPS; ++s) {
        int cur = s & 1;
        bool more = (s + 1) < KSTEPS;
        if (more) load_step(s + 1);

        half8 af  = *(const half8*)((const char*)&Al[cur][0] + a_off);
        half8 bf0 = *(const half8*)((const char*)&Bl[cur][0] + b_off0);
        half8 bf1 = *(const half8*)((const char*)&Bl[cur][0] + b_off1);
        acc0 = __builtin_amdgcn_mfma_f32_16x16x32_f16(af, bf0, acc0, 0, 0, 0);
        acc1 = __builtin_amdgcn_mfma_f32_16x16x32_f16(af, bf1, acc1, 0, 0, 0);

        if (more) store_lds(1 - cur);
        __syncthreads();
    }

    // ---- fused LSTM cell epilogue ----
    int c = bm * 8 + wm * 4 + kq;
    float bi = lbias[c];
    float bf_ = lbias[256 + c];
    float bo = lbias[512 + c];
    float bg = lbias[768 + c];

#pragma unroll
    for (int cN = 0; cN < 2; ++cN) {
        f32x4 a = cN ? acc1 : acc0;
        int pxg = px0 + cN * 16 + acol;
        size_t off = (size_t)img * 65536 + (size_t)c * 256 + pxg;
        float zi = a[0] + bi;
        float zf = a[1] + bf_;
        float zo = a[2] + bo;
        float zg = a[3] + bg;
        float cold = cstate[off];
        float cn = sigmoidf_(zf) * cold + sigmoidf_(zi) * tanhf_(zg);
        float hn = sigmoidf_(zo) * tanhf_(cn);
        cstate[off] = cn;
        hdst[(size_t)img * hds + (size_t)c * 256 + pxg] = (_Float16)hn;
        if (WRITE_SEQ) {
            outseq[(size_t)img * osb + (size_t)c * 256 + pxg] = hn;
            if (outlast)
                outlast[(size_t)img * 65536 + (size_t)c * 256 + pxg] = hn;
        }
    }
}

// ---------------------------------------------------------------------------
extern "C" void kernel_launch(void* const* d_in, const int* in_sizes, int n_in,
                              void* d_out, int out_size, void* d_ws, size_t ws_size,
                              hipStream_t stream)
{
    const float* x   = (const float*)d_in[0];
    const float* w0  = (const float*)d_in[1];
    const float* b0  = (const float*)d_in[2];
    const float* g0  = (const float*)d_in[3];
    const float* be0 = (const float*)d_in[4];
    const float* m0  = (const float*)d_in[5];
    const float* v0  = (const float*)d_in[6];
    const float* w1  = (const float*)d_in[7];
    const float* b1  = (const float*)d_in[8];
    const float* g1  = (const float*)d_in[9];
    const float* be1 = (const float*)d_in[10];
    const float* m1  = (const float*)d_in[11];
    const float* v1  = (const float*)d_in[12];
    const float* w2  = (const float*)d_in[13];
    const float* b2  = (const float*)d_in[14];
    const float* g2  = (const float*)d_in[15];
    const float* be2 = (const float*)d_in[16];
    const float* m2  = (const float*)d_in[17];
    const float* v2  = (const float*)d_in[18];
    const float* lw0 = (const float*)d_in[19];
    const float* lb0 = (const float*)d_in[20];
    const float* lw1 = (const float*)d_in[21];
    const float* lb1 = (const float*)d_in[22];

    float* out = (float*)d_out;   // fp32 output

    // ---- workspace layout (bytes), peak ≈ 27.6 MiB ----
    char* base = (char*)d_ws;
    _Float16* Wp0   = (_Float16*)(base);               // 9,437,184
    _Float16* Wp1   = (_Float16*)(base + 9437184);     // 9,437,184
    _Float16* y2h   = (_Float16*)(base + 18874368);    // 4,194,304 (32 img fp16)
    _Float16* h0s   = (_Float16*)(base + 23068672);    // 4,194,304 ([b][t][c][px])
    _Float16* hb1a  = (_Float16*)(base + 27262976);    //   262,144 (layer-1 ping)
    _Float16* hz16  = (_Float16*)(base + 27525120);    //   131,072 (zero page)
    float*    cst0  = (float*)(base + 27656192);       //   524,288
    float*    cst1  = (float*)(base + 28180480);       //   524,288
    _Float16* hb1b  = (_Float16*)(base + 28704768);    //   262,144 (layer-1 pong)
    // CNN-phase-only scratch (overlaps Wp0/Wp1 region in time):
    float* y0g = (float*)(base);                       // 8,388,608
    float* y1g = (float*)(base + 8388608);             // 4,194,304

    // ---- CNN encoder, 4 groups of 8 images; block3 emits fp16 ----
    for (int g = 0; g < 4; ++g) {
        const float* xg = x + (size_t)g * 8 * 16384;
        cnn_block_kernel<1, 64, 128, 8, float><<<8 * 8 * 16, 256, 0, stream>>>(
            xg, w0, b0, g0, be0, m0, v0, y0g);
        cnn_block_kernel<64, 128, 64, 8, float><<<8 * 16 * 4, 256, 0, stream>>>(
            y0g, w1, b1, g1, be1, m1, v1, y1g);
        cnn_block_kernel<128, 256, 32, 4, _Float16><<<8 * 64 * 1, 256, 0, stream>>>(
            y1g, w2, b2, g2, be2, m2, v2, y2h + (size_t)g * 8 * 65536);
    }

    // ---- weight prep (after CNN: overwrites CNN scratch region) ----
    wprep_kernel<<<2304, 256, 0, stream>>>(lw0, Wp0);
    wprep_kernel<<<2304, 256, 0, stream>>>(lw1, Wp1);

    // zero: hz16 + cst0 + cst1 (contiguous)
    hipMemsetAsync(hz16, 0, (size_t)(131072 + 524288 + 524288), stream);

    const long IS = 16 * 65536;   // img(b) stride in y2h / h0s (elements)

    // ---- ConvLSTM layer 0 (fused conv+cell) ----
    for (int t = 0; t < 16; ++t) {
        const _Float16* hprev = (t == 0) ? hz16 : (h0s + (size_t)(t - 1) * 65536);
        long hstride = (t == 0) ? 0 : IS;
        lstm_step_kernel<false><<<512, 128, 0, stream>>>(
            Wp0, lb0,
            y2h + (size_t)t * 65536, IS,
            hprev, hstride,
            cst0,
            h0s + (size_t)t * 65536, IS,
            nullptr, 0, nullptr);
    }

    // ---- ConvLSTM layer 1 (fused; ping-pong h state — fixes replay race) ----
    for (int t = 0; t < 16; ++t) {
        const _Float16* hprev = (t == 0) ? hz16 : ((t & 1) ? hb1a : hb1b);
        _Float16*       hcur  = (t & 1) ? hb1b : hb1a;
        long hstride = (t == 0) ? 0 : 65536;
        lstm_step_kernel<true><<<512, 128, 0, stream>>>(
            Wp1, lb1,
            h0s + (size_t)t * 65536, IS,
            hprev, hstride,
            cst1,
            hcur, 65536,
            out + (size_t)t * 65536, 1048576,
            (t == 15) ? (out + 2097152) : nullptr);
    }
}

// Round 6
// 2908.056 us; speedup vs baseline: 5.5267x; 1.2965x over previous
//
#include <hip/hip_runtime.h>
#include <hip/hip_bf16.h>
#include <cstddef>
#include <cstdint>

#define BN_EPS 1e-5f

typedef __attribute__((ext_vector_type(8))) _Float16 half8;
typedef __attribute__((ext_vector_type(4))) _Float16 half4;
typedef __attribute__((ext_vector_type(4))) float f32x4;

#define GLOBAL_AS __attribute__((address_space(1)))
#define LDS_AS    __attribute__((address_space(3)))

__device__ __forceinline__ void gload_lds16(const void* g, void* l) {
    __builtin_amdgcn_global_load_lds((const GLOBAL_AS uint32_t*)g,
                                     (LDS_AS uint32_t*)l, 16, 0, 0);
}

__device__ __forceinline__ float sigmoidf_(float x) {
    return 1.f / (1.f + __expf(-x));
}
__device__ __forceinline__ float tanhf_(float x) {
    float e = __expf(2.f * x);
    return 1.f - 2.f / (e + 1.f);
}

// ---------------------------------------------------------------------------
// Fused conv3x3(SAME) + bias + BN + ReLU + maxpool2x2 block (scalar, fp32).
// One thread per pooled output pixel; OCB output channels per block.
// PXC=true: output stored [img][pix][oc] (fp16, vectorized half4 store).
// ---------------------------------------------------------------------------
template <int CI, int OC, int S, int OCB, bool PXC, typename OT>
__global__ __launch_bounds__(256) void cnn_block_kernel(
    const float* __restrict__ in, const float* __restrict__ w,
    const float* __restrict__ bias, const float* __restrict__ g,
    const float* __restrict__ be, const float* __restrict__ m,
    const float* __restrict__ v, OT* __restrict__ out)
{
    constexpr int PS  = S / 2;
    constexpr int NQ  = (PS * PS) / 256;
    constexpr int NOG = OC / OCB;
    __shared__ float wl[OCB * CI * 9];

    int bid  = blockIdx.x;
    int quad = bid % NQ;
    int t2   = bid / NQ;
    int ocg  = t2 % NOG;
    int img  = t2 / NOG;
    int tid  = threadIdx.x;
    int oc0  = ocg * OCB;

    const float* wsrc = w + (size_t)oc0 * CI * 9;
    for (int i = tid; i < OCB * CI * 9; i += 256) wl[i] = wsrc[i];
    __syncthreads();

    int pp = quad * 256 + tid;
    int pr = pp / PS, pc = pp % PS;
    int r0 = 2 * pr - 1, c0 = 2 * pc - 1;

    int  roff[4], coff[4];
    bool rok[4], cok[4];
#pragma unroll
    for (int i = 0; i < 4; i++) {
        int rr = r0 + i; rok[i] = (rr >= 0 && rr < S); roff[i] = min(max(rr, 0), S - 1) * S;
        int cc = c0 + i; cok[i] = (cc >= 0 && cc < S); coff[i] = min(max(cc, 0), S - 1);
    }

    float acc[OCB][4];
#pragma unroll
    for (int o = 0; o < OCB; o++)
#pragma unroll
        for (int j = 0; j < 4; j++) acc[o][j] = 0.f;

    const float* ip = in + (size_t)img * CI * S * S;
    for (int ci = 0; ci < CI; ++ci) {
        float patch[4][4];
#pragma unroll
        for (int iy = 0; iy < 4; iy++)
#pragma unroll
            for (int ix = 0; ix < 4; ix++) {
                float val = ip[roff[iy] + coff[ix]];
                patch[iy][ix] = (rok[iy] && cok[ix]) ? val : 0.f;
            }
#pragma unroll
        for (int o = 0; o < OCB; o++) {
            const float* wp = wl + ((size_t)o * CI + ci) * 9;
#pragma unroll
            for (int ky = 0; ky < 3; ky++)
#pragma unroll
                for (int kx = 0; kx < 3; kx++) {
                    float ww = wp[ky * 3 + kx];
                    acc[o][0] += ww * patch[ky][kx];
                    acc[o][1] += ww * patch[ky][kx + 1];
                    acc[o][2] += ww * patch[ky + 1][kx];
                    acc[o][3] += ww * patch[ky + 1][kx + 1];
                }
        }
        ip += S * S;
    }

    float mxv[OCB];
#pragma unroll
    for (int o = 0; o < OCB; o++) {
        int oc = oc0 + o;
        float scale = g[oc] * rsqrtf(v[oc] + BN_EPS);
        float shift = be[oc] - m[oc] * scale + bias[oc] * scale;
        float r00 = fmaxf(acc[o][0] * scale + shift, 0.f);
        float r01 = fmaxf(acc[o][1] * scale + shift, 0.f);
        float r10 = fmaxf(acc[o][2] * scale + shift, 0.f);
        float r11 = fmaxf(acc[o][3] * scale + shift, 0.f);
        mxv[o] = fmaxf(fmaxf(r00, r01), fmaxf(r10, r11));
    }

    if constexpr (PXC) {
        static_assert(OCB == 4, "PXC path assumes OCB=4");
        half4 hv;
#pragma unroll
        for (int o = 0; o < 4; o++) hv[o] = (_Float16)mxv[o];
        *(half4*)(&out[((size_t)img * (PS * PS) + pp) * OC + oc0]) = hv;
    } else {
#pragma unroll
        for (int o = 0; o < OCB; o++)
            out[((size_t)(img * OC + oc0 + o) * PS + pr) * PS + pc] = (OT)mxv[o];
    }
}

// ---------------------------------------------------------------------------
// Weight permute+convert with baked-in LDS XOR swizzle:
// physical chunk kcp at row holds logical chunk kcl = kcp ^ ((row>>1)&3)
// within each 32-k cell. Logical k = part*2304 + tap*256 + ci.
// ---------------------------------------------------------------------------
__global__ __launch_bounds__(256) void wprep_kernel(
    const float* __restrict__ W, _Float16* __restrict__ Wp)
{
    int idx   = blockIdx.x * 256 + threadIdx.x;   // 0 .. 1024*576-1
    int row   = idx / 576;
    int chunk = idx % 576;
    int k0    = chunk * 8;
    int kcell = k0 >> 5;
    int kcp   = (k0 >> 3) & 3;
    int kcl   = kcp ^ ((row >> 1) & 3);
    int klog  = kcell * 32 + kcl * 8;
    int c = row >> 2, ggate = row & 3;
    int zc = ggate * 256 + c;
    int part = (klog >= 2304) ? 1 : 0;
    int rem  = klog - part * 2304;
    int tap  = rem >> 8;
    int ci   = rem & 255;
    const float* src = W + (size_t)zc * 4608 + (size_t)(part * 256 + ci) * 9 + tap;
    _Float16* dst = Wp + (size_t)row * 4608 + k0;
#pragma unroll
    for (int j = 0; j < 8; ++j) dst[j] = (_Float16)src[(size_t)j * 9];
}

// ---------------------------------------------------------------------------
// Fused ConvLSTM step: implicit-GEMM conv3x3 (M=1024 gate-interleaved rows,
// N=512 = 2 img x 256 px, K=4608) + LSTM cell epilogue. fp16 MFMA 16x16x32.
// Images are [img][pix][ch] fp16 (ch contiguous). Staging via global_load_lds
// (linear LDS; swizzle baked into the global source address / Wp layout).
// 128 threads = 2 waves. Grid: 512 blocks = 32 (M) x 16 (N).
// ---------------------------------------------------------------------------
template <bool WRITE_SEQ>
__global__ __launch_bounds__(128) void lstm_step_kernel(
    const _Float16* __restrict__ Wp, const float* __restrict__ lbias,
    const _Float16* __restrict__ xsrc, long xs,
    const _Float16* __restrict__ hsrc, long hs,
    const _Float16* __restrict__ zpage,
    float* __restrict__ cstate,
    _Float16* __restrict__ hdst, long hds,
    float* __restrict__ outseq, long osb,
    float* __restrict__ outlast)
{
    __shared__ _Float16 Al[2][2048];   // [32 rows][32 k], x2 buffers (linear)
    __shared__ _Float16 Bl[2][2048];   // [32 px][32 k]

    const int tid = threadIdx.x;
    const int bm  = blockIdx.x & 31;
    const int bnb = blockIdx.x >> 5;        // 0..15
    const int img = bnb >> 3;               // 0..1
    const int px0 = (bnb & 7) * 32;

    const int srow = tid >> 2;              // 0..31 (A-row / B-pixel)
    const int kc   = tid & 3;               // physical 8-half chunk
    const int kcs  = kc ^ ((srow >> 1) & 3);  // logical chunk this lane gathers (B)
    const int wid  = tid >> 6;              // wave id

    const _Float16* aptr = Wp + (size_t)(bm * 32 + srow) * 4608 + kc * 8;

    const int p_pix = px0 + srow;
    const int py = p_pix >> 4, px = p_pix & 15;

    const _Float16* srcX = xsrc + (size_t)img * xs;
    const _Float16* srcH = hsrc + (size_t)img * hs;

    // fragment read offsets (bytes), XOR-swizzled
    const int lane = tid & 63;
    const int kq   = lane >> 4;
    const int acol = lane & 15;
    const int arow = wid * 16 + acol;
    const int a_off  = arow * 64 + ((kq ^ ((arow >> 1) & 3)) << 4);
    const int b_off0 = acol * 64 + ((kq ^ ((acol >> 1) & 3)) << 4);
    const int brow1  = 16 + acol;
    const int b_off1 = brow1 * 64 + ((kq ^ ((brow1 >> 1) & 3)) << 4);

    f32x4 acc0 = {0.f, 0.f, 0.f, 0.f};
    f32x4 acc1 = {0.f, 0.f, 0.f, 0.f};

    const int KSTEPS = 144;   // 4608 / 32

    // issue async loads for K-step s into LDS buffer buf
    auto stage = [&](int s, int buf) {
        // A: 2KB tile, linear per lane
        gload_lds16(aptr + (size_t)s * 32, (char*)&Al[buf][0] + wid * 1024);
        // B: one 16B ch-contiguous gather per lane; OOB -> zero page
        int part = (s >= 72) ? 1 : 0;
        int ss   = s - part * 72;
        int tap  = ss >> 3;
        int cc   = ss & 7;
        int dy = tap / 3 - 1, dx = tap - (tap / 3) * 3 - 1;
        int yy = py + dy, xx = px + dx;
        bool ok = (yy >= 0) && (yy < 16) && (xx >= 0) && (xx < 16);
        const _Float16* base = ok ? ((part ? srcH : srcX) + (yy * 16 + xx) * 256)
                                  : zpage;
        gload_lds16(base + cc * 32 + kcs * 8, (char*)&Bl[buf][0] + wid * 1024);
    };

    stage(0, 0);
    __syncthreads();

    for (int s = 0; s < KSTEPS; ++s) {
        int cur = s & 1;
        if (s + 1 < KSTEPS) stage(s + 1, cur ^ 1);

        half8 af  = *(const half8*)((const char*)&Al[cur][0] + a_off);
        half8 bf0 = *(const half8*)((const char*)&Bl[cur][0] + b_off0);
        half8 bf1 = *(const half8*)((const char*)&Bl[cur][0] + b_off1);
        acc0 = __builtin_amdgcn_mfma_f32_16x16x32_f16(af, bf0, acc0, 0, 0, 0);
        acc1 = __builtin_amdgcn_mfma_f32_16x16x32_f16(af, bf1, acc1, 0, 0, 0);

        __syncthreads();
    }

    // ---- fused LSTM cell epilogue ----
    int c = bm * 8 + wid * 4 + kq;
    float bi  = lbias[c];
    float bf_ = lbias[256 + c];
    float bo  = lbias[512 + c];
    float bg  = lbias[768 + c];

#pragma unroll
    for (int cN = 0; cN < 2; ++cN) {
        f32x4 a = cN ? acc1 : acc0;
        int pxg = px0 + cN * 16 + acol;
        size_t off = (size_t)img * 65536 + (size_t)c * 256 + pxg;
        float zi = a[0] + bi;
        float zf = a[1] + bf_;
        float zo = a[2] + bo;
        float zg = a[3] + bg;
        float cold = cstate[off];
        float cn = sigmoidf_(zf) * cold + sigmoidf_(zi) * tanhf_(zg);
        float hn = sigmoidf_(zo) * tanhf_(cn);
        cstate[off] = cn;
        hdst[(size_t)img * hds + (size_t)pxg * 256 + c] = (_Float16)hn;  // [px][ch]
        if (WRITE_SEQ) {
            outseq[(size_t)img * osb + (size_t)c * 256 + pxg] = hn;      // [ch][px]
            if (outlast)
                outlast[(size_t)img * 65536 + (size_t)c * 256 + pxg] = hn;
        }
    }
}

// ---------------------------------------------------------------------------
extern "C" void kernel_launch(void* const* d_in, const int* in_sizes, int n_in,
                              void* d_out, int out_size, void* d_ws, size_t ws_size,
                              hipStream_t stream)
{
    const float* x   = (const float*)d_in[0];
    const float* w0  = (const float*)d_in[1];
    const float* b0  = (const float*)d_in[2];
    const float* g0  = (const float*)d_in[3];
    const float* be0 = (const float*)d_in[4];
    const float* m0  = (const float*)d_in[5];
    const float* v0  = (const float*)d_in[6];
    const float* w1  = (const float*)d_in[7];
    const float* b1  = (const float*)d_in[8];
    const float* g1  = (const float*)d_in[9];
    const float* be1 = (const float*)d_in[10];
    const float* m1  = (const float*)d_in[11];
    const float* v1  = (const float*)d_in[12];
    const float* w2  = (const float*)d_in[13];
    const float* b2  = (const float*)d_in[14];
    const float* g2  = (const float*)d_in[15];
    const float* be2 = (const float*)d_in[16];
    const float* m2  = (const float*)d_in[17];
    const float* v2  = (const float*)d_in[18];
    const float* lw0 = (const float*)d_in[19];
    const float* lb0 = (const float*)d_in[20];
    const float* lw1 = (const float*)d_in[21];
    const float* lb1 = (const float*)d_in[22];

    float* out = (float*)d_out;   // fp32 output

    // ---- workspace layout (bytes), peak ≈ 28.97 MiB (unchanged) ----
    char* base = (char*)d_ws;
    _Float16* Wp0   = (_Float16*)(base);               // 9,437,184
    _Float16* Wp1   = (_Float16*)(base + 9437184);     // 9,437,184
    _Float16* y2h   = (_Float16*)(base + 18874368);    // 4,194,304 (32 img [px][ch])
    _Float16* h0s   = (_Float16*)(base + 23068672);    // 4,194,304 ([b][t][px][ch])
    _Float16* hb1a  = (_Float16*)(base + 27262976);    //   262,144 (layer-1 ping)
    _Float16* hz16  = (_Float16*)(base + 27525120);    //   131,072 (zero page)
    float*    cst0  = (float*)(base + 27656192);       //   524,288
    float*    cst1  = (float*)(base + 28180480);       //   524,288
    _Float16* hb1b  = (_Float16*)(base + 28704768);    //   262,144 (layer-1 pong)
    // CNN-phase-only scratch (dead before Wp/LSTM regions are written):
    float* y1all = (float*)(base);                     // 16,777,216 (32 img)
    float* y0g   = (float*)(base + 16777216);          //  8,388,608 (8-img group)

    // ---- CNN: blocks 1-2 per 8-img group; block 3 merged over 32 img ----
    for (int g = 0; g < 4; ++g) {
        const float* xg = x + (size_t)g * 8 * 16384;
        cnn_block_kernel<1, 64, 128, 8, false, float><<<8 * 8 * 16, 256, 0, stream>>>(
            xg, w0, b0, g0, be0, m0, v0, y0g);
        cnn_block_kernel<64, 128, 64, 8, false, float><<<8 * 16 * 4, 256, 0, stream>>>(
            y0g, w1, b1, g1, be1, m1, v1, y1all + (size_t)g * 8 * 131072);
    }
    cnn_block_kernel<128, 256, 32, 4, true, _Float16><<<32 * 64, 256, 0, stream>>>(
        y1all, w2, b2, g2, be2, m2, v2, y2h);

    // ---- weight prep (after CNN: overwrites CNN scratch region) ----
    wprep_kernel<<<2304, 256, 0, stream>>>(lw0, Wp0);
    wprep_kernel<<<2304, 256, 0, stream>>>(lw1, Wp1);

    // zero: hz16 + cst0 + cst1 (contiguous)
    hipMemsetAsync(hz16, 0, (size_t)(131072 + 524288 + 524288), stream);

    const long IS = 16 * 65536;   // img(b) stride in y2h / h0s (elements)

    // ---- ConvLSTM layer 0 ----
    for (int t = 0; t < 16; ++t) {
        const _Float16* hprev = (t == 0) ? hz16 : (h0s + (size_t)(t - 1) * 65536);
        long hstride = (t == 0) ? 0 : IS;
        lstm_step_kernel<false><<<512, 128, 0, stream>>>(
            Wp0, lb0,
            y2h + (size_t)t * 65536, IS,
            hprev, hstride, hz16,
            cst0,
            h0s + (size_t)t * 65536, IS,
            nullptr, 0, nullptr);
    }

    // ---- ConvLSTM layer 1 (ping-pong h state) ----
    for (int t = 0; t < 16; ++t) {
        const _Float16* hprev = (t == 0) ? hz16 : ((t & 1) ? hb1a : hb1b);
        _Float16*       hcur  = (t & 1) ? hb1b : hb1a;
        long hstride = (t == 0) ? 0 : 65536;
        lstm_step_kernel<true><<<512, 128, 0, stream>>>(
            Wp1, lb1,
            h0s + (size_t)t * 65536, IS,
            hprev, hstride, hz16,
            cst1,
            hcur, 65536,
            out + (size_t)t * 65536, 1048576,
            (t == 15) ? (out + 2097152) : nullptr);
    }
}

// Round 7
// 1782.014 us; speedup vs baseline: 9.0190x; 1.6319x over previous
//
#include <hip/hip_runtime.h>
#include <hip/hip_bf16.h>
#include <cstddef>
#include <cstdint>

#define BN_EPS 1e-5f

typedef __attribute__((ext_vector_type(8))) _Float16 half8;
typedef __attribute__((ext_vector_type(4))) _Float16 half4;
typedef __attribute__((ext_vector_type(4))) float f32x4;

#define GLOBAL_AS __attribute__((address_space(1)))
#define LDS_AS    __attribute__((address_space(3)))

__device__ __forceinline__ void gload_lds16(const void* g, void* l) {
    __builtin_amdgcn_global_load_lds((const GLOBAL_AS uint32_t*)g,
                                     (LDS_AS uint32_t*)l, 16, 0, 0);
}

__device__ __forceinline__ float sigmoidf_(float x) {
    return 1.f / (1.f + __expf(-x));
}
__device__ __forceinline__ float tanhf_(float x) {
    float e = __expf(2.f * x);
    return 1.f - 2.f / (e + 1.f);
}

// ---------------------------------------------------------------------------
// Block-1 CNN (CI=1): scalar conv3x3 + BN + ReLU + pool. One thread per
// pooled pixel, OCB=8 out channels; emits fp16 [img][pooled_px][ch] (half8).
// ---------------------------------------------------------------------------
template <int CI, int OC, int S, int OCB>
__global__ __launch_bounds__(256) void cnn_block1_kernel(
    const float* __restrict__ in, const float* __restrict__ w,
    const float* __restrict__ bias, const float* __restrict__ g,
    const float* __restrict__ be, const float* __restrict__ m,
    const float* __restrict__ v, _Float16* __restrict__ out)
{
    constexpr int PS  = S / 2;
    constexpr int NQ  = (PS * PS) / 256;
    constexpr int NOG = OC / OCB;
    __shared__ float wl[OCB * CI * 9];

    int bid  = blockIdx.x;
    int quad = bid % NQ;
    int t2   = bid / NQ;
    int ocg  = t2 % NOG;
    int img  = t2 / NOG;
    int tid  = threadIdx.x;
    int oc0  = ocg * OCB;

    const float* wsrc = w + (size_t)oc0 * CI * 9;
    for (int i = tid; i < OCB * CI * 9; i += 256) wl[i] = wsrc[i];
    __syncthreads();

    int pp = quad * 256 + tid;
    int pr = pp / PS, pc = pp % PS;
    int r0 = 2 * pr - 1, c0 = 2 * pc - 1;

    int  roff[4], coff[4];
    bool rok[4], cok[4];
#pragma unroll
    for (int i = 0; i < 4; i++) {
        int rr = r0 + i; rok[i] = (rr >= 0 && rr < S); roff[i] = min(max(rr, 0), S - 1) * S;
        int cc = c0 + i; cok[i] = (cc >= 0 && cc < S); coff[i] = min(max(cc, 0), S - 1);
    }

    float acc[OCB][4];
#pragma unroll
    for (int o = 0; o < OCB; o++)
#pragma unroll
        for (int j = 0; j < 4; j++) acc[o][j] = 0.f;

    const float* ip = in + (size_t)img * CI * S * S;
    for (int ci = 0; ci < CI; ++ci) {
        float patch[4][4];
#pragma unroll
        for (int iy = 0; iy < 4; iy++)
#pragma unroll
            for (int ix = 0; ix < 4; ix++) {
                float val = ip[roff[iy] + coff[ix]];
                patch[iy][ix] = (rok[iy] && cok[ix]) ? val : 0.f;
            }
#pragma unroll
        for (int o = 0; o < OCB; o++) {
            const float* wp = wl + ((size_t)o * CI + ci) * 9;
#pragma unroll
            for (int ky = 0; ky < 3; ky++)
#pragma unroll
                for (int kx = 0; kx < 3; kx++) {
                    float ww = wp[ky * 3 + kx];
                    acc[o][0] += ww * patch[ky][kx];
                    acc[o][1] += ww * patch[ky][kx + 1];
                    acc[o][2] += ww * patch[ky + 1][kx];
                    acc[o][3] += ww * patch[ky + 1][kx + 1];
                }
        }
        ip += S * S;
    }

    half8 hv;
#pragma unroll
    for (int o = 0; o < OCB; o++) {
        int oc = oc0 + o;
        float scale = g[oc] * rsqrtf(v[oc] + BN_EPS);
        float shift = be[oc] - m[oc] * scale + bias[oc] * scale;
        float r00 = fmaxf(acc[o][0] * scale + shift, 0.f);
        float r01 = fmaxf(acc[o][1] * scale + shift, 0.f);
        float r10 = fmaxf(acc[o][2] * scale + shift, 0.f);
        float r11 = fmaxf(acc[o][3] * scale + shift, 0.f);
        hv[o] = (_Float16)fmaxf(fmaxf(r00, r01), fmaxf(r10, r11));
    }
    *(half8*)(&out[((size_t)img * (PS * PS) + pp) * OC + oc0]) = hv;
}

// ---------------------------------------------------------------------------
// Conv weight prep (generic): Wc[oc][k=tap*CI+ci] fp16, XOR-swizzle baked:
// physical chunk kcp at row oc holds logical chunk kcp ^ ((oc>>1)&3).
// Source W is OIHW fp32.
// ---------------------------------------------------------------------------
template <int OC, int CI>
__global__ __launch_bounds__(256) void wprep_conv_kernel(
    const float* __restrict__ W, _Float16* __restrict__ Wc)
{
    constexpr int K  = CI * 9;
    constexpr int CH = K / 8;
    int idx = blockIdx.x * 256 + threadIdx.x;
    if (idx >= OC * CH) return;
    int oc = idx / CH, chunk = idx % CH;
    int k0   = chunk * 8;
    int kcp  = (k0 >> 3) & 3;
    int kcl  = kcp ^ ((oc >> 1) & 3);
    int klog = (k0 & ~31) | (kcl << 3);
    int tap = klog / CI, ci = klog % CI;
    const float* src = W + ((size_t)oc * CI + ci) * 9 + tap;
    _Float16* dst = Wc + (size_t)oc * K + k0;
#pragma unroll
    for (int j = 0; j < 8; ++j) dst[j] = (_Float16)src[(size_t)j * 9];
}

// ---------------------------------------------------------------------------
// LSTM weight prep: Wp[row'=c*4+gate][k'=part*2304+tap*256+ci] fp16,
// same baked XOR swizzle. (unchanged from round 6 — verified)
// ---------------------------------------------------------------------------
__global__ __launch_bounds__(256) void wprep_kernel(
    const float* __restrict__ W, _Float16* __restrict__ Wp)
{
    int idx   = blockIdx.x * 256 + threadIdx.x;   // 0 .. 1024*576-1
    int row   = idx / 576;
    int chunk = idx % 576;
    int k0    = chunk * 8;
    int kcell = k0 >> 5;
    int kcp   = (k0 >> 3) & 3;
    int kcl   = kcp ^ ((row >> 1) & 3);
    int klog  = kcell * 32 + kcl * 8;
    int c = row >> 2, ggate = row & 3;
    int zc = ggate * 256 + c;
    int part = (klog >= 2304) ? 1 : 0;
    int rem  = klog - part * 2304;
    int tap  = rem >> 8;
    int ci   = rem & 255;
    const float* src = W + (size_t)zc * 4608 + (size_t)(part * 256 + ci) * 9 + tap;
    _Float16* dst = Wp + (size_t)row * 4608 + k0;
#pragma unroll
    for (int j = 0; j < 8; ++j) dst[j] = (_Float16)src[(size_t)j * 9];
}

// ---------------------------------------------------------------------------
// MFMA implicit-GEMM conv3x3(SAME) + BN + ReLU + pool2x2 (blocks 2 and 3).
// M = OC, N = 32 img * SIN*SIN conv px (pool-grouped: n = pooled_px*4+quad),
// K = CI*9. Input fp16 [img][pix][CI]; output fp16 [img][pooled_px][OC].
// 128 threads = 2 waves, 32x32 tile; double-buffered global_load_lds staging
// (round-6-verified skeleton). Grid: (OC/32) * (N/32).
// ---------------------------------------------------------------------------
template <int CI, int OC, int SIN>
__global__ __launch_bounds__(128) void conv_mfma_kernel(
    const _Float16* __restrict__ Wc, const _Float16* __restrict__ in,
    const float* __restrict__ bias, const float* __restrict__ g,
    const float* __restrict__ be, const float* __restrict__ m,
    const float* __restrict__ v, const _Float16* __restrict__ zpage,
    _Float16* __restrict__ out)
{
    constexpr int K    = CI * 9;
    constexpr int KS   = K / 32;
    constexpr int SPT  = CI / 32;        // K-steps per tap
    constexpr int NPX  = SIN * SIN;
    constexpr int POOL = SIN / 2;
    constexpr int NPP  = NPX / 4;
    constexpr int MB   = OC / 32;

    __shared__ _Float16 Al[2][1024];
    __shared__ _Float16 Bl[2][1024];

    const int tid = threadIdx.x;
    const int bm  = blockIdx.x % MB;
    const int nb  = blockIdx.x / MB;
    const int n0  = nb * 32;
    const int img = n0 / NPX;
    const int r   = n0 - img * NPX;      // img-local, multiple of 32

    const int srow = tid >> 2;
    const int kc   = tid & 3;
    const int kcs  = kc ^ ((srow >> 1) & 3);
    const int wid  = tid >> 6;

    const _Float16* aptr = Wc + (size_t)(bm * 32 + srow) * K + kc * 8;

    // conv pixel for this lane's B-gather (pool-grouped order)
    const int rn   = r + srow;
    const int ppix = rn >> 2, quad = rn & 3;
    const int y = (ppix / POOL) * 2 + (quad >> 1);
    const int x = (ppix % POOL) * 2 + (quad & 1);
    const _Float16* imgbase = in + (size_t)img * NPX * CI;

    // fragment read offsets (bytes), XOR-swizzled
    const int lane = tid & 63;
    const int kq   = lane >> 4;
    const int acol = lane & 15;
    const int arow = wid * 16 + acol;
    const int a_off  = arow * 64 + ((kq ^ ((arow >> 1) & 3)) << 4);
    const int b_off0 = acol * 64 + ((kq ^ ((acol >> 1) & 3)) << 4);
    const int brow1  = 16 + acol;
    const int b_off1 = brow1 * 64 + ((kq ^ ((brow1 >> 1) & 3)) << 4);

    f32x4 acc0 = {0.f, 0.f, 0.f, 0.f};
    f32x4 acc1 = {0.f, 0.f, 0.f, 0.f};

    auto stage = [&](int s, int buf) {
        gload_lds16(aptr + (size_t)s * 32, (char*)&Al[buf][0] + wid * 1024);
        int tap = s / SPT;
        int ci0 = (s % SPT) * 32;
        int dy = tap / 3 - 1, dx = tap - (tap / 3) * 3 - 1;
        int yy = y + dy, xx = x + dx;
        bool ok = (yy >= 0) && (yy < SIN) && (xx >= 0) && (xx < SIN);
        const _Float16* base = ok ? (imgbase + (size_t)(yy * SIN + xx) * CI) : zpage;
        gload_lds16(base + ci0 + kcs * 8, (char*)&Bl[buf][0] + wid * 1024);
    };

    stage(0, 0);
    __syncthreads();

    for (int s = 0; s < KS; ++s) {
        int cur = s & 1;
        if (s + 1 < KS) stage(s + 1, cur ^ 1);

        half8 af  = *(const half8*)((const char*)&Al[cur][0] + a_off);
        half8 bf0 = *(const half8*)((const char*)&Bl[cur][0] + b_off0);
        half8 bf1 = *(const half8*)((const char*)&Bl[cur][0] + b_off1);
        acc0 = __builtin_amdgcn_mfma_f32_16x16x32_f16(af, bf0, acc0, 0, 0, 0);
        acc1 = __builtin_amdgcn_mfma_f32_16x16x32_f16(af, bf1, acc1, 0, 0, 0);

        __syncthreads();
    }

    // ---- epilogue: BN + ReLU + pool(4 adjacent N cols) + half4 store ----
    const int oc0w = bm * 32 + wid * 16 + kq * 4;
    float sc[4], sh[4];
#pragma unroll
    for (int j = 0; j < 4; j++) {
        int oc = oc0w + j;
        sc[j] = g[oc] * rsqrtf(v[oc] + BN_EPS);
        sh[j] = be[oc] - m[oc] * sc[j] + bias[oc] * sc[j];
    }

#pragma unroll
    for (int cN = 0; cN < 2; ++cN) {
        f32x4 a = cN ? acc1 : acc0;
        half4 hv;
#pragma unroll
        for (int j = 0; j < 4; j++) {
            float val = fmaxf(a[j] * sc[j] + sh[j], 0.f);
            val = fmaxf(val, __shfl_xor(val, 1));
            val = fmaxf(val, __shfl_xor(val, 2));
            hv[j] = (_Float16)val;
        }
        if ((acol & 3) == 0) {
            int pl = (r + cN * 16 + acol) >> 2;
            *(half4*)(&out[((size_t)img * NPP + pl) * OC + oc0w]) = hv;
        }
    }
}

// ---------------------------------------------------------------------------
// Fused ConvLSTM step: implicit-GEMM conv3x3 (M=1024 gate-interleaved rows,
// N=512, K=4608) + LSTM cell epilogue. fp16 MFMA 16x16x32.
// 4-buffer, 3-ahead pipeline with counted vmcnt + raw s_barrier (stage issued
// AFTER the barrier -> 4 buffers suffice; reader lgkm-drains before its next
// barrier, writer stages only after that barrier).
// ---------------------------------------------------------------------------
template <bool WRITE_SEQ>
__global__ __launch_bounds__(128) void lstm_step_kernel(
    const _Float16* __restrict__ Wp, const float* __restrict__ lbias,
    const _Float16* __restrict__ xsrc, long xs,
    const _Float16* __restrict__ hsrc, long hs,
    const _Float16* __restrict__ zpage,
    float* __restrict__ cstate,
    _Float16* __restrict__ hdst, long hds,
    float* __restrict__ outseq, long osb,
    float* __restrict__ outlast)
{
    __shared__ _Float16 Al[4][1024];
    __shared__ _Float16 Bl[4][1024];

    const int tid = threadIdx.x;
    const int bm  = blockIdx.x & 31;
    const int bnb = blockIdx.x >> 5;        // 0..15
    const int img = bnb >> 3;               // 0..1
    const int px0 = (bnb & 7) * 32;

    const int srow = tid >> 2;
    const int kc   = tid & 3;
    const int kcs  = kc ^ ((srow >> 1) & 3);
    const int wid  = tid >> 6;

    const _Float16* aptr = Wp + (size_t)(bm * 32 + srow) * 4608 + kc * 8;

    const int p_pix = px0 + srow;
    const int py = p_pix >> 4, px = p_pix & 15;

    const _Float16* srcX = xsrc + (size_t)img * xs;
    const _Float16* srcH = hsrc + (size_t)img * hs;

    const int lane = tid & 63;
    const int kq   = lane >> 4;
    const int acol = lane & 15;
    const int arow = wid * 16 + acol;
    const int a_off  = arow * 64 + ((kq ^ ((arow >> 1) & 3)) << 4);
    const int b_off0 = acol * 64 + ((kq ^ ((acol >> 1) & 3)) << 4);
    const int brow1  = 16 + acol;
    const int b_off1 = brow1 * 64 + ((kq ^ ((brow1 >> 1) & 3)) << 4);

    f32x4 acc0 = {0.f, 0.f, 0.f, 0.f};
    f32x4 acc1 = {0.f, 0.f, 0.f, 0.f};

    const int KSTEPS = 144;   // 4608 / 32

    auto stage = [&](int s, int buf) {
        gload_lds16(aptr + (size_t)s * 32, (char*)&Al[buf][0] + wid * 1024);
        int part = (s >= 72) ? 1 : 0;
        int ss   = s - part * 72;
        int tap  = ss >> 3;
        int cc   = ss & 7;
        int dy = tap / 3 - 1, dx = tap - (tap / 3) * 3 - 1;
        int yy = py + dy, xx = px + dx;
        bool ok = (yy >= 0) && (yy < 16) && (xx >= 0) && (xx < 16);
        const _Float16* base = ok ? ((part ? srcH : srcX) + (size_t)(yy * 16 + xx) * 256)
                                  : zpage;
        gload_lds16(base + cc * 32 + kcs * 8, (char*)&Bl[buf][0] + wid * 1024);
    };

    stage(0, 0);
    stage(1, 1);
    stage(2, 2);

    for (int s = 0; s < KSTEPS; ++s) {
        __builtin_amdgcn_sched_barrier(0);
        if (s < KSTEPS - 2)       asm volatile("s_waitcnt vmcnt(4)" ::: "memory");
        else if (s == KSTEPS - 2) asm volatile("s_waitcnt vmcnt(2)" ::: "memory");
        else                      asm volatile("s_waitcnt vmcnt(0)" ::: "memory");
        __builtin_amdgcn_s_barrier();
        if (s + 3 < KSTEPS) stage(s + 3, (s + 3) & 3);

        const int cur = s & 3;
        half8 af  = *(const half8*)((const char*)&Al[cur][0] + a_off);
        half8 bf0 = *(const half8*)((const char*)&Bl[cur][0] + b_off0);
        half8 bf1 = *(const half8*)((const char*)&Bl[cur][0] + b_off1);
        acc0 = __builtin_amdgcn_mfma_f32_16x16x32_f16(af, bf0, acc0, 0, 0, 0);
        acc1 = __builtin_amdgcn_mfma_f32_16x16x32_f16(af, bf1, acc1, 0, 0, 0);
    }

    // ---- fused LSTM cell epilogue ----
    int c = bm * 8 + wid * 4 + kq;
    float bi  = lbias[c];
    float bf_ = lbias[256 + c];
    float bo  = lbias[512 + c];
    float bg  = lbias[768 + c];

#pragma unroll
    for (int cN = 0; cN < 2; ++cN) {
        f32x4 a = cN ? acc1 : acc0;
        int pxg = px0 + cN * 16 + acol;
        size_t off = (size_t)img * 65536 + (size_t)c * 256 + pxg;
        float zi = a[0] + bi;
        float zf = a[1] + bf_;
        float zo = a[2] + bo;
        float zg = a[3] + bg;
        float cold = cstate[off];
        float cn = sigmoidf_(zf) * cold + sigmoidf_(zi) * tanhf_(zg);
        float hn = sigmoidf_(zo) * tanhf_(cn);
        cstate[off] = cn;
        hdst[(size_t)img * hds + (size_t)pxg * 256 + c] = (_Float16)hn;  // [px][ch]
        if (WRITE_SEQ) {
            outseq[(size_t)img * osb + (size_t)c * 256 + pxg] = hn;      // [ch][px]
            if (outlast)
                outlast[(size_t)img * 65536 + (size_t)c * 256 + pxg] = hn;
        }
    }
}

// ---------------------------------------------------------------------------
extern "C" void kernel_launch(void* const* d_in, const int* in_sizes, int n_in,
                              void* d_out, int out_size, void* d_ws, size_t ws_size,
                              hipStream_t stream)
{
    const float* x   = (const float*)d_in[0];
    const float* w0  = (const float*)d_in[1];
    const float* b0  = (const float*)d_in[2];
    const float* g0  = (const float*)d_in[3];
    const float* be0 = (const float*)d_in[4];
    const float* m0  = (const float*)d_in[5];
    const float* v0  = (const float*)d_in[6];
    const float* w1  = (const float*)d_in[7];
    const float* b1  = (const float*)d_in[8];
    const float* g1  = (const float*)d_in[9];
    const float* be1 = (const float*)d_in[10];
    const float* m1  = (const float*)d_in[11];
    const float* v1  = (const float*)d_in[12];
    const float* w2  = (const float*)d_in[13];
    const float* b2  = (const float*)d_in[14];
    const float* g2  = (const float*)d_in[15];
    const float* be2 = (const float*)d_in[16];
    const float* m2  = (const float*)d_in[17];
    const float* v2  = (const float*)d_in[18];
    const float* lw0 = (const float*)d_in[19];
    const float* lb0 = (const float*)d_in[20];
    const float* lw1 = (const float*)d_in[21];
    const float* lb1 = (const float*)d_in[22];

    float* out = (float*)d_out;   // fp32 output

    // ---- workspace layout (bytes), peak ≈ 30.33 MiB ----
    char* base = (char*)d_ws;
    // LSTM-phase regions (overlay y0/y1 after they die):
    _Float16* Wp0  = (_Float16*)(base);                // [0, 9437184)
    _Float16* Wp1  = (_Float16*)(base + 9437184);      // [9437184, 18874368)
    _Float16* h0s  = (_Float16*)(base + 18874368);     // [18874368, 23068672)
    _Float16* y2h  = (_Float16*)(base + 25165824);     // [25165824, 29360128)
    _Float16* Wc2  = (_Float16*)(base + 29360128);     // 147,456
    _Float16* Wc3  = (_Float16*)(base + 29507584);     // 589,824
    _Float16* zpg  = (_Float16*)(base + 30097408);     // 131,072 (zero page)
    _Float16* hb1a = (_Float16*)(base + 30228480);     // 262,144
    _Float16* hb1b = (_Float16*)(base + 30490624);     // 262,144
    float*    cst0 = (float*)(base + 30752768);        // 524,288
    float*    cst1 = (float*)(base + 31277056);        // 524,288
    // CNN-phase-only regions:
    _Float16* y0   = (_Float16*)(base);                // [0, 16777216)  32x4096x64
    _Float16* y1   = (_Float16*)(base + 16777216);     // [16777216, 25165824) 32x1024x128

    // zero page first (conv_mfma + lstm t=0 read it)
    hipMemsetAsync(zpg, 0, 131072, stream);

    // ---- CNN encoder ----
    cnn_block1_kernel<1, 64, 128, 8><<<32 * 8 * 16, 256, 0, stream>>>(
        x, w0, b0, g0, be0, m0, v0, y0);
    wprep_conv_kernel<128, 64><<<36, 256, 0, stream>>>(w1, Wc2);
    conv_mfma_kernel<64, 128, 64><<<4 * 4096, 128, 0, stream>>>(
        Wc2, y0, b1, g1, be1, m1, v1, zpg, y1);
    wprep_conv_kernel<256, 128><<<144, 256, 0, stream>>>(w2, Wc3);
    conv_mfma_kernel<128, 256, 32><<<8 * 1024, 128, 0, stream>>>(
        Wc3, y1, b2, g2, be2, m2, v2, zpg, y2h);

    // ---- LSTM weight prep (y0/y1 dead now) ----
    wprep_kernel<<<2304, 256, 0, stream>>>(lw0, Wp0);
    wprep_kernel<<<2304, 256, 0, stream>>>(lw1, Wp1);

    // zero c-states (contiguous)
    hipMemsetAsync(cst0, 0, (size_t)2 * 524288, stream);

    const long IS = 16 * 65536;   // img(b) stride in y2h / h0s (elements)

    // ---- ConvLSTM layer 0 ----
    for (int t = 0; t < 16; ++t) {
        const _Float16* hprev = (t == 0) ? zpg : (h0s + (size_t)(t - 1) * 65536);
        long hstride = (t == 0) ? 0 : IS;
        lstm_step_kernel<false><<<512, 128, 0, stream>>>(
            Wp0, lb0,
            y2h + (size_t)t * 65536, IS,
            hprev, hstride, zpg,
            cst0,
            h0s + (size_t)t * 65536, IS,
            nullptr, 0, nullptr);
    }

    // ---- ConvLSTM layer 1 (ping-pong h state) ----
    for (int t = 0; t < 16; ++t) {
        const _Float16* hprev = (t == 0) ? zpg : ((t & 1) ? hb1a : hb1b);
        _Float16*       hcur  = (t & 1) ? hb1b : hb1a;
        long hstride = (t == 0) ? 0 : 65536;
        lstm_step_kernel<true><<<512, 128, 0, stream>>>(
            Wp1, lb1,
            h0s + (size_t)t * 65536, IS,
            hprev, hstride, zpg,
            cst1,
            hcur, 65536,
            out + (size_t)t * 65536, 1048576,
            (t == 15) ? (out + 2097152) : nullptr);
    }
}